// Round 6
// baseline (92.897 us; speedup 1.0000x reference)
//
#include <hip/hip_runtime.h>

// out[b,k,h,w] = w[k,0]*side5 + w[k,1]*side4 + w[k,2]*side1 + w[k,3]*side2
//              + w[k,4]*side3 + bias[k]
// B=8, K=19, H=W=512.
// Each thread: TWO float4 spatial slots, loops k with an EXPLICIT software
// pipeline (prefetch k+1's 4 loads into named regs while computing k) so
// 4 loads are always in flight during compute. nt-load split removed (R5
// showed FETCH_SIZE unchanged -> hint is null on gfx950 MALL). nt stores
// kept (output never re-read).

#define KK   19
#define HW4  65536      // (512*512)/4 float4s per plane

typedef float f32x4 __attribute__((ext_vector_type(4)));

__global__ __launch_bounds__(256) void grouped_conv_fuse_kernel(
    const float* __restrict__ s1, const float* __restrict__ s2,
    const float* __restrict__ s3, const float* __restrict__ s4,
    const float* __restrict__ s5, const float* __restrict__ w,
    const float* __restrict__ bias, float* __restrict__ out)
{
    const f32x4* __restrict__ v1 = (const f32x4*)s1;
    const f32x4* __restrict__ v2 = (const f32x4*)s2;
    const f32x4* __restrict__ v3 = (const f32x4*)s3;
    const f32x4* __restrict__ v4 = (const f32x4*)s4;
    const f32x4* __restrict__ v5 = (const f32x4*)s5;
    f32x4* __restrict__ vo = (f32x4*)out;

    // 1024 blocks: 128 blocks per batch, each block covers 512 float4 slots
    int b   = blockIdx.x >> 7;                            // 0..7
    int sp0 = ((blockIdx.x & 127) << 9) + threadIdx.x;    // first slot
    int si0 = (b << 16) + sp0;
    int si1 = si0 + 256;

    f32x4 p1 = v1[si0], q1 = v1[si1];
    f32x4 p2 = v2[si0], q2 = v2[si1];
    f32x4 p3 = v3[si0], q3 = v3[si1];

    long base0 = (long)b * KK * HW4 + sp0;
    long base1 = base0 + 256;

    // prologue: load k=0
    f32x4 x5a = v5[base0], x5b = v5[base1];
    f32x4 x4a = v4[base0], x4b = v4[base1];

    for (int k = 0; k < KK - 1; ++k) {
        long n0 = base0 + (long)(k + 1) * HW4;
        long n1 = base1 + (long)(k + 1) * HW4;
        // issue k+1 loads FIRST -> in flight during k's compute+store
        f32x4 y5a = v5[n0], y5b = v5[n1];
        f32x4 y4a = v4[n0], y4b = v4[n1];

        float w0 = w[k * 5 + 0], w1 = w[k * 5 + 1], w2 = w[k * 5 + 2];
        float w3 = w[k * 5 + 3], w4 = w[k * 5 + 4], bb = bias[k];

        long i0 = base0 + (long)k * HW4;
        long i1 = base1 + (long)k * HW4;
        f32x4 oa = w0 * x5a + w1 * x4a + w2 * p1 + w3 * p2 + w4 * p3 + bb;
        f32x4 ob = w0 * x5b + w1 * x4b + w2 * q1 + w3 * q2 + w4 * q3 + bb;
        __builtin_nontemporal_store(oa, &vo[i0]);
        __builtin_nontemporal_store(ob, &vo[i1]);

        x5a = y5a; x5b = y5b; x4a = y4a; x4b = y4b;
    }

    // epilogue: k = KK-1
    {
        const int k = KK - 1;
        float w0 = w[k * 5 + 0], w1 = w[k * 5 + 1], w2 = w[k * 5 + 2];
        float w3 = w[k * 5 + 3], w4 = w[k * 5 + 4], bb = bias[k];
        long i0 = base0 + (long)k * HW4;
        long i1 = base1 + (long)k * HW4;
        f32x4 oa = w0 * x5a + w1 * x4a + w2 * p1 + w3 * p2 + w4 * p3 + bb;
        f32x4 ob = w0 * x5b + w1 * x4b + w2 * q1 + w3 * q2 + w4 * q3 + bb;
        __builtin_nontemporal_store(oa, &vo[i0]);
        __builtin_nontemporal_store(ob, &vo[i1]);
    }
}

extern "C" void kernel_launch(void* const* d_in, const int* in_sizes, int n_in,
                              void* d_out, int out_size, void* d_ws, size_t ws_size,
                              hipStream_t stream) {
    const float* s1   = (const float*)d_in[0];
    const float* s2   = (const float*)d_in[1];
    const float* s3   = (const float*)d_in[2];
    const float* s4   = (const float*)d_in[3];
    const float* s5   = (const float*)d_in[4];
    const float* w    = (const float*)d_in[5];
    const float* bias = (const float*)d_in[6];
    float* out        = (float*)d_out;

    grouped_conv_fuse_kernel<<<1024, 256, 0, stream>>>(s1, s2, s3, s4, s5, w, bias, out);
}

// Round 7
// 88.163 us; speedup vs baseline: 1.0537x; 1.0537x over previous
//
#include <hip/hip_runtime.h>

// out[b,k,h,w] = w[k,0]*side5 + w[k,1]*side4 + w[k,2]*side1 + w[k,3]*side2
//              + w[k,4]*side3 + bias[k]
// B=8, K=19, H=W=512.
// R5 structure (2 float4 slots/thread, 4 loads in flight, nt stores) PLUS
// k-range split across 2 block groups -> 2048 blocks for 2x wave TLP.
// Explicit SW pipeline (R6) reverted: compiler sank the prefetch (VGPR
// stayed 32) and the rotation hurt. nt loads proven null on gfx950.

#define KK   19
#define HW4  65536      // (512*512)/4 float4s per plane

typedef float f32x4 __attribute__((ext_vector_type(4)));

__global__ __launch_bounds__(256) void grouped_conv_fuse_kernel(
    const float* __restrict__ s1, const float* __restrict__ s2,
    const float* __restrict__ s3, const float* __restrict__ s4,
    const float* __restrict__ s5, const float* __restrict__ w,
    const float* __restrict__ bias, float* __restrict__ out)
{
    const f32x4* __restrict__ v1 = (const f32x4*)s1;
    const f32x4* __restrict__ v2 = (const f32x4*)s2;
    const f32x4* __restrict__ v3 = (const f32x4*)s3;
    const f32x4* __restrict__ v4 = (const f32x4*)s4;
    const f32x4* __restrict__ v5 = (const f32x4*)s5;
    f32x4* __restrict__ vo = (f32x4*)out;

    // 2048 blocks = 8 batches x 2 k-groups x 128 spatial chunks
    int b   = blockIdx.x >> 8;                            // 0..7
    int kg  = (blockIdx.x >> 7) & 1;                      // 0..1
    int sp0 = ((blockIdx.x & 127) << 9) + threadIdx.x;    // first slot
    int si0 = (b << 16) + sp0;
    int si1 = si0 + 256;

    f32x4 p1 = v1[si0], q1 = v1[si1];
    f32x4 p2 = v2[si0], q2 = v2[si1];
    f32x4 p3 = v3[si0], q3 = v3[si1];

    long base0 = (long)b * KK * HW4 + sp0;
    long base1 = base0 + 256;

    if (kg == 0) {
        #pragma unroll 2
        for (int k = 0; k < 10; ++k) {
            long i0 = base0 + (long)k * HW4;
            long i1 = base1 + (long)k * HW4;
            f32x4 x5a = v5[i0], x5b = v5[i1];
            f32x4 x4a = v4[i0], x4b = v4[i1];

            float w0 = w[k * 5 + 0], w1 = w[k * 5 + 1], w2 = w[k * 5 + 2];
            float w3 = w[k * 5 + 3], w4 = w[k * 5 + 4], bb = bias[k];

            f32x4 oa = w0 * x5a + w1 * x4a + w2 * p1 + w3 * p2 + w4 * p3 + bb;
            f32x4 ob = w0 * x5b + w1 * x4b + w2 * q1 + w3 * q2 + w4 * q3 + bb;
            __builtin_nontemporal_store(oa, &vo[i0]);
            __builtin_nontemporal_store(ob, &vo[i1]);
        }
    } else {
        #pragma unroll 2
        for (int k = 10; k < KK; ++k) {
            long i0 = base0 + (long)k * HW4;
            long i1 = base1 + (long)k * HW4;
            f32x4 x5a = v5[i0], x5b = v5[i1];
            f32x4 x4a = v4[i0], x4b = v4[i1];

            float w0 = w[k * 5 + 0], w1 = w[k * 5 + 1], w2 = w[k * 5 + 2];
            float w3 = w[k * 5 + 3], w4 = w[k * 5 + 4], bb = bias[k];

            f32x4 oa = w0 * x5a + w1 * x4a + w2 * p1 + w3 * p2 + w4 * p3 + bb;
            f32x4 ob = w0 * x5b + w1 * x4b + w2 * q1 + w3 * q2 + w4 * q3 + bb;
            __builtin_nontemporal_store(oa, &vo[i0]);
            __builtin_nontemporal_store(ob, &vo[i1]);
        }
    }
}

extern "C" void kernel_launch(void* const* d_in, const int* in_sizes, int n_in,
                              void* d_out, int out_size, void* d_ws, size_t ws_size,
                              hipStream_t stream) {
    const float* s1   = (const float*)d_in[0];
    const float* s2   = (const float*)d_in[1];
    const float* s3   = (const float*)d_in[2];
    const float* s4   = (const float*)d_in[3];
    const float* s5   = (const float*)d_in[4];
    const float* w    = (const float*)d_in[5];
    const float* bias = (const float*)d_in[6];
    float* out        = (float*)d_out;

    grouped_conv_fuse_kernel<<<2048, 256, 0, stream>>>(s1, s2, s3, s4, s5, w, bias, out);
}